// Round 4
// baseline (961.677 us; speedup 1.0000x reference)
//
#include <hip/hip_runtime.h>

#define NN 100000
#define NE 1600000
#define DD 64
#define NBKT 800     // buckets of BSZ nodes; 800*125 == NN exactly
#define BSZ 125
#define PTILE 6250   // edges per partition block; 256*6250 == NE exactly

__device__ __forceinline__ float fsig(float x) {
    return __fdividef(1.0f, 1.0f + __expf(-x));
}
__device__ __forceinline__ float ftanh(float x) {
    return __fdividef(2.0f, 1.0f + __expf(-2.0f * x)) - 1.0f;
}
__device__ __forceinline__ unsigned int bf16rne(float a) {
    unsigned int u = __float_as_uint(a);
    return (u + 0x7fffu + ((u >> 16) & 1u)) >> 16;
}

// ---- Bucket histogram (LDS-staged; 800 global atomics per block) --------
__global__ __launch_bounds__(256) void hist_k(const int* __restrict__ dst,
                                              unsigned* __restrict__ bcnt) {
    __shared__ unsigned cnt[NBKT];
    const int tid = threadIdx.x;
    for (int i = tid; i < NBKT; i += 256) cnt[i] = 0u;
    __syncthreads();
    const int base = blockIdx.x * PTILE;
    for (int i = tid; i < PTILE; i += 256)
        atomicAdd(&cnt[(unsigned)dst[base + i] / BSZ], 1u);
    __syncthreads();
    for (int i = tid; i < NBKT; i += 256)
        if (cnt[i]) atomicAdd(&bcnt[i], cnt[i]);
}

// ---- Exclusive scan over 800 bucket counts (single block) ---------------
__global__ __launch_bounds__(1024) void scan_k(const unsigned* __restrict__ bcnt,
                                               unsigned* __restrict__ start,
                                               unsigned* __restrict__ gcur) {
    __shared__ unsigned s[1024];
    const int t = threadIdx.x;
    const unsigned v = (t < NBKT) ? bcnt[t] : 0u;
    s[t] = v;
    __syncthreads();
    for (int off = 1; off < 1024; off <<= 1) {
        const unsigned tmp = (t >= off) ? s[t - off] : 0u;
        __syncthreads();
        s[t] += tmp;
        __syncthreads();
    }
    if (t < NBKT) { start[t] = s[t] - v; gcur[t] = s[t] - v; }
    if (t == NBKT - 1) start[NBKT] = s[t];   // == NE
}

// ---- Partition edges into buckets ---------------------------------------
// Per block: LDS tile-counts -> ONE range-reservation atomic per nonempty
// bucket -> scatter where each block x bucket run is ~8 edges = 64B
// contiguous (write amp ~2x, vs 8x for the old full per-node sort).
__global__ __launch_bounds__(256) void part_k(const int* __restrict__ src,
                                              const int* __restrict__ dst,
                                              const float* __restrict__ ew,
                                              unsigned* __restrict__ gcur,
                                              uint2* __restrict__ pairs) {
    __shared__ unsigned cnt[NBKT];
    __shared__ unsigned basep[NBKT];
    __shared__ unsigned off[NBKT];
    const int tid = threadIdx.x;
    for (int i = tid; i < NBKT; i += 256) { cnt[i] = 0u; off[i] = 0u; }
    __syncthreads();
    const int base = blockIdx.x * PTILE;
    for (int i = tid; i < PTILE; i += 256)
        atomicAdd(&cnt[(unsigned)dst[base + i] / BSZ], 1u);
    __syncthreads();
    for (int i = tid; i < NBKT; i += 256)
        basep[i] = cnt[i] ? atomicAdd(&gcur[i], cnt[i]) : 0u;
    __syncthreads();
    for (int i = tid; i < PTILE; i += 256) {
        const int e = base + i;
        const unsigned d = (unsigned)dst[e];
        const unsigned b = d / BSZ;
        const unsigned p = basep[b] + atomicAdd(&off[b], 1u);
        // pack: src (17 bits) | local-dst (7 bits) << 17 ; w bits
        pairs[p] = make_uint2((unsigned)src[e] | ((d - b * BSZ) << 17),
                              __float_as_uint(ew[e]));
    }
}

// ---- Bucket accumulate: LDS f32 atomics, zero global atomics ------------
// One block per bucket (125 nodes, 32,000B LDS acc -> 5 blocks/CU).
// lane = channel; 2-way bank aliasing on sacc = free.
__global__ __launch_bounds__(256) void accum_k(const float* __restrict__ h,
                                               const uint2* __restrict__ pairs,
                                               const unsigned* __restrict__ start,
                                               float* __restrict__ hnew) {
    __shared__ float sacc[BSZ * DD];
    const int tid = threadIdx.x;
    const int lane = tid & 63;
    const int wave = tid >> 6;
    for (int i = tid; i < BSZ * DD; i += 256) sacc[i] = 0.0f;
    __syncthreads();
    const unsigned s0 = start[blockIdx.x];
    const unsigned s1 = start[blockIdx.x + 1];
    for (unsigned cbase = s0 + (unsigned)(wave << 6); cbase < s1; cbase += 256u) {
        const int m = (int)min(64u, s1 - cbase);
        uint2 pr = make_uint2(0u, 0u);
        if (lane < m) pr = pairs[cbase + lane];      // coalesced 8B/lane
        if (m == 64) {
            #pragma unroll 8
            for (int j = 0; j < 64; ++j) {
                const unsigned x = (unsigned)__shfl((int)pr.x, j);
                const float    w = __shfl(__uint_as_float(pr.y), j);
                atomicAdd(&sacc[(x >> 17) * DD + lane],
                          w * h[(x & 0x1FFFFu) * DD + lane]);
            }
        } else {
            for (int j = 0; j < m; ++j) {
                const unsigned x = (unsigned)__shfl((int)pr.x, j);
                const float    w = __shfl(__uint_as_float(pr.y), j);
                atomicAdd(&sacc[(x >> 17) * DD + lane],
                          w * h[(x & 0x1FFFFu) * DD + lane]);
            }
        }
    }
    __syncthreads();
    const unsigned nb = (unsigned)blockIdx.x * (BSZ * DD);
    for (int i = tid; i < BSZ * DD; i += 256)
        hnew[nb + i] = sacc[i];                      // coalesced, once per node
}

// ---- GRU cell (unchanged from R3: 53,248B LDS -> 3 blocks/CU) -----------
__global__ __launch_bounds__(256, 3) void gru_k(
    const float* hnew, const float* __restrict__ h,
    const float* __restrict__ Wih, const float* __restrict__ Whh,
    const float* __restrict__ bih, const float* __restrict__ bhh,
    float* out)
{
    __shared__ unsigned WtI[32][192];  // [k2][row], bf16x2 along k
    __shared__ unsigned WtH[32][192];
    __shared__ unsigned xh[16][64];    // (bf16(x)<<16)|bf16(h)

    const int tid = threadIdx.x;
    for (int f = tid; f < 192 * 32; f += 256) {
        const int row = f >> 5, k2 = f & 31;
        const float2 wi = *(const float2*)(Wih + row * 64 + 2 * k2);
        const float2 wh = *(const float2*)(Whh + row * 64 + 2 * k2);
        WtI[k2][row] = bf16rne(wi.x) | (bf16rne(wi.y) << 16);
        WtH[k2][row] = bf16rne(wh.x) | (bf16rne(wh.y) << 16);
    }
    __syncthreads();

    const int lane = tid & 63;
    const int w4 = (tid >> 6) << 2;

    const float b_ir = bih[lane], b_iz = bih[64 + lane], b_in = bih[128 + lane];
    const float b_hr = bhh[lane], b_hz = bhh[64 + lane], b_hn = bhh[128 + lane];

    for (int g = blockIdx.x; g < NN / 16; g += gridDim.x) {
        const int nb = g * 16 + w4;
        float hreg[4];
        #pragma unroll
        for (int i = 0; i < 4; ++i) {
            const float xv = hnew[(nb + i) * DD + lane];
            hreg[i] = h[(nb + i) * DD + lane];
            xh[w4 + i][lane] = (bf16rne(xv) << 16) | bf16rne(hreg[i]);
        }
        float air[4], aiz[4], ain[4], ahr[4], ahz[4], ahn[4];
        #pragma unroll
        for (int i = 0; i < 4; ++i) {
            air[i] = b_ir; aiz[i] = b_iz; ain[i] = b_in;
            ahr[i] = b_hr; ahz[i] = b_hz; ahn[i] = b_hn;
        }
        #pragma unroll 8
        for (int k2 = 0; k2 < 32; ++k2) {
            const unsigned uir = WtI[k2][lane];
            const unsigned uiz = WtI[k2][64 + lane];
            const unsigned uin = WtI[k2][128 + lane];
            const unsigned uhr = WtH[k2][lane];
            const unsigned uhz = WtH[k2][64 + lane];
            const unsigned uhn = WtH[k2][128 + lane];
            const float wir0 = __uint_as_float(uir << 16), wir1 = __uint_as_float(uir & 0xffff0000u);
            const float wiz0 = __uint_as_float(uiz << 16), wiz1 = __uint_as_float(uiz & 0xffff0000u);
            const float win0 = __uint_as_float(uin << 16), win1 = __uint_as_float(uin & 0xffff0000u);
            const float whr0 = __uint_as_float(uhr << 16), whr1 = __uint_as_float(uhr & 0xffff0000u);
            const float whz0 = __uint_as_float(uhz << 16), whz1 = __uint_as_float(uhz & 0xffff0000u);
            const float whn0 = __uint_as_float(uhn << 16), whn1 = __uint_as_float(uhn & 0xffff0000u);
            #pragma unroll
            for (int i = 0; i < 4; ++i) {
                const uint2 u2 = *(const uint2*)(&xh[w4 + i][2 * k2]);
                const float x0 = __uint_as_float(u2.x & 0xffff0000u);
                const float h0 = __uint_as_float(u2.x << 16);
                const float x1 = __uint_as_float(u2.y & 0xffff0000u);
                const float h1 = __uint_as_float(u2.y << 16);
                air[i] = fmaf(x0, wir0, air[i]); air[i] = fmaf(x1, wir1, air[i]);
                aiz[i] = fmaf(x0, wiz0, aiz[i]); aiz[i] = fmaf(x1, wiz1, aiz[i]);
                ain[i] = fmaf(x0, win0, ain[i]); ain[i] = fmaf(x1, win1, ain[i]);
                ahr[i] = fmaf(h0, whr0, ahr[i]); ahr[i] = fmaf(h1, whr1, ahr[i]);
                ahz[i] = fmaf(h0, whz0, ahz[i]); ahz[i] = fmaf(h1, whz1, ahz[i]);
                ahn[i] = fmaf(h0, whn0, ahn[i]); ahn[i] = fmaf(h1, whn1, ahn[i]);
            }
        }
        #pragma unroll
        for (int i = 0; i < 4; ++i) {
            const float r  = fsig(air[i] + ahr[i]);
            const float z  = fsig(aiz[i] + ahz[i]);
            const float nv = ftanh(fmaf(r, ahn[i], ain[i]));
            out[(nb + i) * DD + lane] = fmaf(z, hreg[i] - nv, nv);
        }
    }
}

extern "C" void kernel_launch(void* const* d_in, const int* in_sizes, int n_in,
                              void* d_out, int out_size, void* d_ws, size_t ws_size,
                              hipStream_t stream)
{
    const float* h   = (const float*)d_in[0];
    const float* ew  = (const float*)d_in[1];
    const float* Wih = (const float*)d_in[2];
    const float* Whh = (const float*)d_in[3];
    const float* bih = (const float*)d_in[4];
    const float* bhh = (const float*)d_in[5];
    const int*   src = (const int*)d_in[6];
    const int*   dst = (const int*)d_in[7];
    float* out = (float*)d_out;

    // ws layout (~12.82 MB)
    char* ws = (char*)d_ws;
    unsigned* bcnt  = (unsigned*)(ws);            // 3,200 B
    unsigned* start = (unsigned*)(ws + 3200);     // 3,204 B
    unsigned* gcur  = (unsigned*)(ws + 6408);     // 3,200 B
    uint2*    pairs = (uint2*)   (ws + 16384);    // 12.8 MB (8B-aligned)

    hipMemsetAsync(bcnt, 0, NBKT * sizeof(unsigned), stream);
    hist_k <<<256, 256, 0, stream>>>(dst, bcnt);
    scan_k <<<1, 1024, 0, stream>>>(bcnt, start, gcur);
    part_k <<<256, 256, 0, stream>>>(src, dst, ew, gcur, pairs);
    accum_k<<<NBKT, 256, 0, stream>>>(h, pairs, start, out);  // out = hnew scratch
    gru_k  <<<768, 256, 0, stream>>>(out, h, Wih, Whh, bih, bhh, out);
}